// Round 1
// baseline (948.746 us; speedup 1.0000x reference)
//
#include <hip/hip_runtime.h>
#include <hip/hip_bf16.h>

// Ternary-quantized linear: out[M,N] = x[M,K] . W^T,  W[n,k] = q[n,k]*scale[n],
// q in {-1,0,1} packed 4-per-byte (each byte stored as one int32 element).
// Strategy: bf16 MFMA GEMM, q exact in bf16, scale folded into fp32 epilogue.
// Fully fused (no workspace): x fp32->bf16 cast and W unpack (256-entry LDS LUT)
// happen in the staging phase.

#define M_DIM 8192
#define N_DIM 11008
#define K_DIM 4096
#define BM 128
#define BN 128
#define BK 64
#define KT (K_DIM / BK)      // 64
#define NB_N (N_DIM / BN)    // 86
#define NWG ((M_DIM / BM) * NB_N)  // 64*86 = 5504, divisible by 8
#define LDAP 72              // padded LDS row stride in bf16 elems (144 B -> 4-bank rotation/row)

typedef __attribute__((ext_vector_type(8))) short bf16x8;
typedef __attribute__((ext_vector_type(4))) float f32x4;

__device__ inline unsigned short bf16b(float f) {
  union { __hip_bfloat16 h; unsigned short u; } cv;
  cv.h = __float2bfloat16(f);
  return cv.u;
}

__global__ __launch_bounds__(256, 2)
void qlin_mfma_kernel(const float* __restrict__ X, const int* __restrict__ PW,
                      const float* __restrict__ SC, float* __restrict__ OUT) {
  __shared__ unsigned short As[BM * LDAP];  // x tile, bf16 bits
  __shared__ unsigned short Bs[BN * LDAP];  // W tile (ternary as bf16 bits)
  __shared__ uint2 lut[256];                // byte -> 4 bf16 ({-1,0,1})

  const int tid = threadIdx.x;

  // ---- build ternary-unpack LUT (one entry per thread; blockDim == 256) ----
  {
    unsigned int b = (unsigned int)tid;
    unsigned int h[4];
#pragma unroll
    for (int f = 0; f < 4; ++f) {
      unsigned int t = (b >> (2 * f)) & 3u;
      // (q+1): 0 -> -1.0 (0xBF80), 1 -> 0.0, 2 -> +1.0 (0x3F80)
      h[f] = (t == 1u) ? 0u : ((t == 2u) ? 0x3F80u : 0xBF80u);
    }
    lut[tid] = make_uint2(h[0] | (h[1] << 16), h[2] | (h[3] << 16));
  }

  // ---- grid decode: bijective XCD swizzle (5504 % 8 == 0), n-fastest ----
  const int wg = blockIdx.x;
  const int swz = (wg & 7) * (NWG / 8) + (wg >> 3);
  const int bm = swz / NB_N;
  const int bn = swz - bm * NB_N;

  const int lane = tid & 63;
  const int wave = tid >> 6;
  const int wr = wave >> 1;   // 0..1  (row half of 128x128)
  const int wc = wave & 1;    // 0..1  (col half)

  // ---- staging maps ----
  // A: thread -> row (tid>>4) + j*16 (j=0..7), 4 floats at col (tid&15)*4
  const int ar = tid >> 4;            // 0..15
  const int ac = (tid & 15) * 4;      // 0..60
  const float* xptr = X + (size_t)(bm * BM + ar) * K_DIM + ac;
  // B: thread -> row (tid>>2) + j*64 (j=0..1), int4 (=16 weights) at byte-chunk (tid&3)*4
  const int br = tid >> 2;            // 0..63
  const int bc = tid & 3;             // 0..3
  const int* pwptr = PW + (size_t)(bn * BN + br) * (K_DIM / 4) + bc * 4;

  f32x4 acc[4][4];
#pragma unroll
  for (int i = 0; i < 4; ++i)
#pragma unroll
    for (int j = 0; j < 4; ++j) acc[i][j] = (f32x4){0.f, 0.f, 0.f, 0.f};

  float4 av[8];
  int4 bv[2];

  // prologue: loads for kt=0
#pragma unroll
  for (int j = 0; j < 8; ++j) av[j] = *(const float4*)(xptr + (size_t)j * 16 * K_DIM);
#pragma unroll
  for (int j = 0; j < 2; ++j) bv[j] = *(const int4*)(pwptr + (size_t)j * 64 * (K_DIM / 4));

  for (int kt = 0; kt < KT; ++kt) {
    __syncthreads();  // prev-iter LDS reads done (and LUT ready on iter 0)

    // ---- store A tile: fp32 -> bf16, padded rows ----
#pragma unroll
    for (int j = 0; j < 8; ++j) {
      ushort4 hv;
      hv.x = bf16b(av[j].x);
      hv.y = bf16b(av[j].y);
      hv.z = bf16b(av[j].z);
      hv.w = bf16b(av[j].w);
      *(ushort4*)&As[(ar + j * 16) * LDAP + ac] = hv;
    }
    // ---- store B tile: LUT unpack, 16 weights -> 32 B per int4 ----
#pragma unroll
    for (int j = 0; j < 2; ++j) {
      const unsigned int b0 = (unsigned int)bv[j].x & 255u;
      const unsigned int b1 = (unsigned int)bv[j].y & 255u;
      const unsigned int b2 = (unsigned int)bv[j].z & 255u;
      const unsigned int b3 = (unsigned int)bv[j].w & 255u;
      const uint2 l0 = lut[b0], l1 = lut[b1], l2 = lut[b2], l3 = lut[b3];
      unsigned short* dst = &Bs[(br + j * 64) * LDAP + bc * 16];
      *(uint4*)dst = make_uint4(l0.x, l0.y, l1.x, l1.y);
      *(uint4*)(dst + 8) = make_uint4(l2.x, l2.y, l3.x, l3.y);
    }
    __syncthreads();

    // ---- prefetch next tile into regs (overlaps with MFMA below) ----
    if (kt + 1 < KT) {
#pragma unroll
      for (int j = 0; j < 8; ++j)
        av[j] = *(const float4*)(xptr + (kt + 1) * BK + (size_t)j * 16 * K_DIM);
#pragma unroll
      for (int j = 0; j < 2; ++j)
        bv[j] = *(const int4*)(pwptr + (kt + 1) * 16 + (size_t)j * 64 * (K_DIM / 4));
    }

    // ---- compute: 2 x (8 ds_read_b128 + 16 MFMA) per wave ----
#pragma unroll
    for (int kk = 0; kk < 2; ++kk) {
      bf16x8 af[4], bfr[4];
#pragma unroll
      for (int m = 0; m < 4; ++m)
        af[m] = *(const bf16x8*)&As[(wr * 64 + m * 16 + (lane & 15)) * LDAP + kk * 32 + (lane >> 4) * 8];
#pragma unroll
      for (int n = 0; n < 4; ++n)
        bfr[n] = *(const bf16x8*)&Bs[(wc * 64 + n * 16 + (lane & 15)) * LDAP + kk * 32 + (lane >> 4) * 8];
#pragma unroll
      for (int m = 0; m < 4; ++m)
#pragma unroll
        for (int n = 0; n < 4; ++n)
          acc[m][n] = __builtin_amdgcn_mfma_f32_16x16x32_bf16(af[m], bfr[n], acc[m][n], 0, 0, 0);
    }
  }

  // ---- epilogue: acc * scale[col] -> fp32 out ----
  // C/D layout (m89-verified): col = lane&15, row = (lane>>4)*4 + reg
  const int gc0 = bn * BN + wc * 64 + (lane & 15);
  const int gr0 = bm * BM + wr * 64 + ((lane >> 4) << 2);
  float sc[4];
#pragma unroll
  for (int n = 0; n < 4; ++n) sc[n] = SC[gc0 + n * 16];
#pragma unroll
  for (int m = 0; m < 4; ++m)
#pragma unroll
    for (int n = 0; n < 4; ++n)
#pragma unroll
      for (int r = 0; r < 4; ++r)
        OUT[(size_t)(gr0 + m * 16 + r) * N_DIM + gc0 + n * 16] = acc[m][n][r] * sc[n];
}

extern "C" void kernel_launch(void* const* d_in, const int* in_sizes, int n_in,
                              void* d_out, int out_size, void* d_ws, size_t ws_size,
                              hipStream_t stream) {
  const float* x  = (const float*)d_in[0];
  const int*   pw = (const int*)d_in[1];
  const float* sc = (const float*)d_in[2];
  float* out = (float*)d_out;
  (void)d_ws; (void)ws_size; (void)in_sizes; (void)n_in; (void)out_size;
  qlin_mfma_kernel<<<dim3(NWG), dim3(256), 0, stream>>>(x, pw, sc, out);
}

// Round 4
// 933.211 us; speedup vs baseline: 1.0166x; 1.0166x over previous
//
#include <hip/hip_runtime.h>
#include <hip/hip_bf16.h>

// Ternary-quantized linear: out[M,N] = x[M,K] . W^T,  W[n,k] = q[n,k]*scale[n].
// bf16 MFMA GEMM; q exact in bf16; scale folded into fp32 epilogue.
// R2: linear 128B LDS rows + XOR swizzle ((row&7)<<4) on BOTH write and read
//     (reg-staged, so both sides controllable). All LDS ops in 16B chunks ->
//     every quarter-wave is 2-way max = conflict-free.
// R3/R4: identical resubmits (R2/R3 benches died to infra: UnresponsiveContainer).

#define M_DIM 8192
#define N_DIM 11008
#define K_DIM 4096
#define BM 128
#define BN 128
#define BK 64
#define KT (K_DIM / BK)            // 64
#define NB_N (N_DIM / BN)          // 86
#define NWG ((M_DIM / BM) * NB_N)  // 5504, divisible by 8

typedef __attribute__((ext_vector_type(8))) short bf16x8;
typedef __attribute__((ext_vector_type(4))) float f32x4;

__device__ inline unsigned int bf16b(float f) {
  union { __hip_bfloat16 h; unsigned short u; } cv;
  cv.h = __float2bfloat16(f);
  return (unsigned int)cv.u;
}

__global__ __launch_bounds__(256, 2)
void qlin_mfma_kernel(const float* __restrict__ X, const int* __restrict__ PW,
                      const float* __restrict__ SC, float* __restrict__ OUT) {
  __shared__ unsigned short As[BM * BK];  // 16 KB, row stride 128 B, XOR-swizzled
  __shared__ unsigned short Bs[BN * BK];  // 16 KB
  __shared__ uint2 lut[256];              // packed byte -> 4 bf16 ({-1,0,1})

  const int tid = threadIdx.x;

  // ---- ternary-unpack LUT ----
  {
    unsigned int b = (unsigned int)tid;
    unsigned int h[4];
#pragma unroll
    for (int f = 0; f < 4; ++f) {
      unsigned int t = (b >> (2 * f)) & 3u;
      h[f] = (t == 1u) ? 0u : ((t == 2u) ? 0x3F80u : 0xBF80u);
    }
    lut[tid] = make_uint2(h[0] | (h[1] << 16), h[2] | (h[3] << 16));
  }

  // ---- bijective XCD swizzle, n-fastest ----
  const int wg = blockIdx.x;
  const int swz = (wg & 7) * (NWG / 8) + (wg >> 3);
  const int bm = swz / NB_N;
  const int bn = swz - bm * NB_N;

  const int lane = tid & 63;
  const int wave = tid >> 6;
  const int wr = wave >> 1;   // 0..1
  const int wc = wave & 1;    // 0..1

  // ---- A staging map: thread -> (row = (tid>>3)+32j, 16B chunk = tid&7) ----
  const int arow = tid >> 3;            // 0..31
  const int ac8  = tid & 7;             // 0..7
  const float* xptr = X + (size_t)(bm * BM + arow) * K_DIM + ac8 * 8;
  const unsigned int aswz = ((unsigned)arow & 7u) << 4;

  // ---- B staging map: thread -> (row = tid>>1, half = tid&1) ----
  const int brow = tid >> 1;            // 0..127
  const int bh   = tid & 1;             // 0..1
  const int* pwptr = PW + (size_t)(bn * BN + brow) * (K_DIM / 4) + bh * 8;
  const unsigned int bswz = ((unsigned)brow & 7u) << 4;

  f32x4 acc[4][4];
#pragma unroll
  for (int i = 0; i < 4; ++i)
#pragma unroll
    for (int j = 0; j < 4; ++j) acc[i][j] = (f32x4){0.f, 0.f, 0.f, 0.f};

  float4 av[4][2];
  int4 bv[2];

  // prologue loads (kt = 0)
#pragma unroll
  for (int j = 0; j < 4; ++j) {
    av[j][0] = *(const float4*)(xptr + (size_t)(32 * j) * K_DIM);
    av[j][1] = *(const float4*)(xptr + (size_t)(32 * j) * K_DIM + 4);
  }
  bv[0] = *(const int4*)(pwptr);
  bv[1] = *(const int4*)(pwptr + 4);

  for (int kt = 0; kt < KT; ++kt) {
    __syncthreads();  // prev-iter LDS reads done (and LUT ready on iter 0)

    // ---- A store: fp32 -> bf16, 16B swizzled chunks ----
#pragma unroll
    for (int j = 0; j < 4; ++j) {
      uint4 w;
      w.x = bf16b(av[j][0].x) | (bf16b(av[j][0].y) << 16);
      w.y = bf16b(av[j][0].z) | (bf16b(av[j][0].w) << 16);
      w.z = bf16b(av[j][1].x) | (bf16b(av[j][1].y) << 16);
      w.w = bf16b(av[j][1].z) | (bf16b(av[j][1].w) << 16);
      *(uint4*)((char*)As + (arow + 32 * j) * 128 + (((unsigned)ac8 * 16u) ^ aswz)) = w;
    }
    // ---- B store: LUT unpack, 16B swizzled chunks ----
    {
#define BCH(EA, EB, CC) do { \
      uint2 l0 = lut[(unsigned)(EA) & 255u]; \
      uint2 l1 = lut[(unsigned)(EB) & 255u]; \
      uint4 w = make_uint4(l0.x, l0.y, l1.x, l1.y); \
      *(uint4*)((char*)Bs + brow * 128 + ((((unsigned)(bh * 4 + (CC))) * 16u) ^ bswz)) = w; \
    } while (0)
      BCH(bv[0].x, bv[0].y, 0);
      BCH(bv[0].z, bv[0].w, 1);
      BCH(bv[1].x, bv[1].y, 2);
      BCH(bv[1].z, bv[1].w, 3);
#undef BCH
    }
    __syncthreads();

    // ---- prefetch next tile into regs (overlaps MFMA below) ----
    if (kt + 1 < KT) {
#pragma unroll
      for (int j = 0; j < 4; ++j) {
        av[j][0] = *(const float4*)(xptr + (kt + 1) * BK + (size_t)(32 * j) * K_DIM);
        av[j][1] = *(const float4*)(xptr + (kt + 1) * BK + (size_t)(32 * j) * K_DIM + 4);
      }
      bv[0] = *(const int4*)(pwptr + (kt + 1) * 16);
      bv[1] = *(const int4*)(pwptr + (kt + 1) * 16 + 4);
    }

    // ---- compute: 2 x (8 swizzled ds_read_b128 + 16 MFMA) per wave ----
    const unsigned int rswz = ((unsigned)lane & 7u) << 4;
#pragma unroll
    for (int kk = 0; kk < 2; ++kk) {
      bf16x8 af[4], bfr[4];
      const unsigned int coff = (((unsigned)(kk * 4 + (lane >> 4))) * 16u) ^ rswz;
#pragma unroll
      for (int m = 0; m < 4; ++m)
        af[m] = *(const bf16x8*)((const char*)As + (wr * 64 + m * 16 + (lane & 15)) * 128 + coff);
#pragma unroll
      for (int n = 0; n < 4; ++n)
        bfr[n] = *(const bf16x8*)((const char*)Bs + (wc * 64 + n * 16 + (lane & 15)) * 128 + coff);
#pragma unroll
      for (int m = 0; m < 4; ++m)
#pragma unroll
        for (int n = 0; n < 4; ++n)
          acc[m][n] = __builtin_amdgcn_mfma_f32_16x16x32_bf16(af[m], bfr[n], acc[m][n], 0, 0, 0);
    }
  }

  // ---- epilogue: acc * scale[col] -> fp32 out ----
  // C/D layout (m89): col = lane&15, row = (lane>>4)*4 + reg
  const int gc0 = bn * BN + wc * 64 + (lane & 15);
  const int gr0 = bm * BM + wr * 64 + ((lane >> 4) << 2);
  float sc[4];
#pragma unroll
  for (int n = 0; n < 4; ++n) sc[n] = SC[gc0 + n * 16];
#pragma unroll
  for (int m = 0; m < 4; ++m)
#pragma unroll
    for (int n = 0; n < 4; ++n)
#pragma unroll
      for (int r = 0; r < 4; ++r)
        OUT[(size_t)(gr0 + m * 16 + r) * N_DIM + gc0 + n * 16] = acc[m][n][r] * sc[n];
}

extern "C" void kernel_launch(void* const* d_in, const int* in_sizes, int n_in,
                              void* d_out, int out_size, void* d_ws, size_t ws_size,
                              hipStream_t stream) {
  const float* x  = (const float*)d_in[0];
  const int*   pw = (const int*)d_in[1];
  const float* sc = (const float*)d_in[2];
  float* out = (float*)d_out;
  (void)d_ws; (void)ws_size; (void)in_sizes; (void)n_in; (void)out_size;
  qlin_mfma_kernel<<<dim3(NWG), dim3(256), 0, stream>>>(x, pw, sc, out);
}

// Round 5
// 860.398 us; speedup vs baseline: 1.1027x; 1.0846x over previous
//
#include <hip/hip_runtime.h>
#include <hip/hip_bf16.h>

// Ternary-quantized linear: out[M,N] = x[M,K] . W^T,  W[n,k] = q[n,k]*scale[n].
// R5: B stays PACKED (2-bit) in LDS (5KB vs 32KB bf16); fragments unpacked
//     in-register via SWAR: ((u<<s)&0xC000C000)+0x40004000 maps t -> bf16
//     {+2,-0,-2} = -2q exactly (fold -0.5 into scale). No LUT (R4's remaining
//     6.3e7 conflicts were LUT random-access). Tile 128x256, wave tile 64x128:
//     LDS bytes/FLOP cut ~4x -> MFMA-pipe-bound (model: 1034 cyc/block-kt).

#define M_DIM 8192
#define N_DIM 11008
#define K_DIM 4096
#define BM 128
#define BN 256
#define BK 64
#define KT (K_DIM / BK)            // 64
#define NB_N (N_DIM / BN)          // 43
#define NWG ((M_DIM / BM) * NB_N)  // 64*43 = 2752, %8 == 0
#define BSTRIDE 20                 // packed-B LDS row stride (bank = 5*col, conflict-free)

typedef __attribute__((ext_vector_type(8))) short bf16x8;
typedef __attribute__((ext_vector_type(4))) float f32x4;

__device__ inline unsigned int bf16b(float f) {
  union { __hip_bfloat16 h; unsigned short u; } cv;
  cv.h = __float2bfloat16(f);
  return (unsigned int)cv.u;
}

__global__ __launch_bounds__(256, 2)
void qlin_mfma_kernel(const float* __restrict__ X, const int* __restrict__ PW,
                      const float* __restrict__ SC, float* __restrict__ OUT) {
  __shared__ unsigned short As[BM * BK];           // 16 KB bf16, XOR-swizzled rows
  __shared__ unsigned char Bp[BN * BSTRIDE];       // 5 KB packed ternary

  const int tid = threadIdx.x;

  // ---- bijective XCD swizzle, n-fastest (A-panel stays hot in L2) ----
  const int wg = blockIdx.x;
  const int swz = (wg & 7) * (NWG / 8) + (wg >> 3);
  const int bm = swz / NB_N;
  const int bn = swz - bm * NB_N;

  const int lane = tid & 63;
  const int wave = tid >> 6;
  const int wr = wave >> 1;   // 0..1 (M half)
  const int wc = wave & 1;    // 0..1 (N half)

  // ---- A staging map (as R2/R4): row = (tid>>3)+32j, 8-float chunk = tid&7 ----
  const int arow = tid >> 3;            // 0..31
  const int ac8  = tid & 7;             // 0..7
  const float* xptr = X + (size_t)(bm * BM + arow) * K_DIM + ac8 * 8;
  const unsigned int aswz = ((unsigned)arow & 7u) << 4;

  // ---- B staging map: c = tid&3 (4-int32 chunk), rows (tid>>2) + 64j ----
  // global byte b (0..15 within row-tile) -> LDS pos = h*4 + kk*2 + p
  // (kk = b>>3, h = (b&7)>>1, p = b&1); thread's chunk c covers bytes 4c..4c+3:
  //   u_lo = bytes(4c,4c+1) at pos (c&1)*8 + (c>>1)*2 ; u_hi = +4
  const int bc  = tid & 3;
  const int br0 = tid >> 2;             // 0..63
  const int* pwptr = PW + (size_t)(bn * BN + br0) * (K_DIM / 4) + bc * 4;
  const int bwoff = (bc & 1) * 8 + (bc >> 1) * 2;

  f32x4 acc[4][8];
#pragma unroll
  for (int i = 0; i < 4; ++i)
#pragma unroll
    for (int j = 0; j < 8; ++j) acc[i][j] = (f32x4){0.f, 0.f, 0.f, 0.f};

  float4 av[4][2];
  int4 bv[4];

  // prologue loads (kt = 0)
#pragma unroll
  for (int j = 0; j < 4; ++j) {
    av[j][0] = *(const float4*)(xptr + (size_t)(32 * j) * K_DIM);
    av[j][1] = *(const float4*)(xptr + (size_t)(32 * j) * K_DIM + 4);
  }
#pragma unroll
  for (int j = 0; j < 4; ++j)
    bv[j] = *(const int4*)(pwptr + (size_t)(64 * j) * (K_DIM / 4));

  for (int kt = 0; kt < KT; ++kt) {
    __syncthreads();  // prev-iter LDS reads done

    // ---- A store: fp32 -> bf16, 16B swizzled chunks ----
#pragma unroll
    for (int j = 0; j < 4; ++j) {
      uint4 w;
      w.x = bf16b(av[j][0].x) | (bf16b(av[j][0].y) << 16);
      w.y = bf16b(av[j][0].z) | (bf16b(av[j][0].w) << 16);
      w.z = bf16b(av[j][1].x) | (bf16b(av[j][1].y) << 16);
      w.w = bf16b(av[j][1].z) | (bf16b(av[j][1].w) << 16);
      *(uint4*)((char*)As + (arow + 32 * j) * 128 + (((unsigned)ac8 * 16u) ^ aswz)) = w;
    }
    // ---- B store: packed bytes, reordered (kk,h)-major; values are 0..255 ----
#pragma unroll
    for (int j = 0; j < 4; ++j) {
      const unsigned int ulo = (unsigned)bv[j].x | ((unsigned)bv[j].y << 8);
      const unsigned int uhi = (unsigned)bv[j].z | ((unsigned)bv[j].w << 8);
      unsigned char* dst = Bp + (br0 + 64 * j) * BSTRIDE + bwoff;
      *(unsigned short*)(dst)     = (unsigned short)ulo;
      *(unsigned short*)(dst + 4) = (unsigned short)uhi;
    }
    __syncthreads();

    // ---- prefetch next tile into regs (overlaps MFMA below) ----
    if (kt + 1 < KT) {
#pragma unroll
      for (int j = 0; j < 4; ++j) {
        av[j][0] = *(const float4*)(xptr + (kt + 1) * BK + (size_t)(32 * j) * K_DIM);
        av[j][1] = *(const float4*)(xptr + (kt + 1) * BK + (size_t)(32 * j) * K_DIM + 4);
      }
#pragma unroll
      for (int j = 0; j < 4; ++j)
        bv[j] = *(const int4*)(pwptr + (kt + 1) * 16 + (size_t)(64 * j) * (K_DIM / 4));
    }

    // ---- B packed fragment reads: one b32 per n covers kk=0,1 for this lane ----
    const int bh = lane >> 4;                    // 0..3
    const int bcol0 = wc * 128 + (lane & 15);
    unsigned int d[8];
#pragma unroll
    for (int n = 0; n < 8; ++n)
      d[n] = *(const unsigned int*)(Bp + (bcol0 + n * 16) * BSTRIDE + bh * 4);

    // ---- compute: 2 kk x (4 ds_read_b128 A + 8x(unpack+4 MFMA)) ----
    const unsigned int rswz = ((unsigned)lane & 7u) << 4;
#pragma unroll
    for (int kk = 0; kk < 2; ++kk) {
      bf16x8 af[4];
      const unsigned int coff = (((unsigned)(kk * 4 + (lane >> 4))) * 16u) ^ rswz;
#pragma unroll
      for (int m = 0; m < 4; ++m)
        af[m] = *(const bf16x8*)((const char*)As + (wr * 64 + m * 16 + (lane & 15)) * 128 + coff);
#pragma unroll
      for (int n = 0; n < 8; ++n) {
        // 16 bits = 8 ternary weights; map t -> bf16 {+2,-0,-2} = -2q
        const unsigned int w16 = kk ? (d[n] >> 16) : (d[n] & 0xFFFFu);
        const unsigned int u = w16 | (w16 << 14);
        union { uint4 s; bf16x8 v; } bfr;
        bfr.s.x = ((u << 14) & 0xC000C000u) + 0x40004000u;
        bfr.s.y = ((u << 10) & 0xC000C000u) + 0x40004000u;
        bfr.s.z = ((u << 6)  & 0xC000C000u) + 0x40004000u;
        bfr.s.w = ((u << 2)  & 0xC000C000u) + 0x40004000u;
#pragma unroll
        for (int m = 0; m < 4; ++m)
          acc[m][n] = __builtin_amdgcn_mfma_f32_16x16x32_bf16(af[m], bfr.v, acc[m][n], 0, 0, 0);
      }
    }
  }

  // ---- epilogue: acc * (-0.5*scale[col]) -> fp32 out ----
  // C/D layout (m89): col = lane&15, row = (lane>>4)*4 + reg
  const int gc0 = bn * BN + wc * 128 + (lane & 15);
  const int gr0 = bm * BM + wr * 64 + ((lane >> 4) << 2);
  float sc[8];
#pragma unroll
  for (int n = 0; n < 8; ++n) sc[n] = -0.5f * SC[gc0 + n * 16];
#pragma unroll
  for (int m = 0; m < 4; ++m)
#pragma unroll
    for (int n = 0; n < 8; ++n)
#pragma unroll
      for (int r = 0; r < 4; ++r)
        OUT[(size_t)(gr0 + m * 16 + r) * N_DIM + gc0 + n * 16] = acc[m][n][r] * sc[n];
}

extern "C" void kernel_launch(void* const* d_in, const int* in_sizes, int n_in,
                              void* d_out, int out_size, void* d_ws, size_t ws_size,
                              hipStream_t stream) {
  const float* x  = (const float*)d_in[0];
  const int*   pw = (const int*)d_in[1];
  const float* sc = (const float*)d_in[2];
  float* out = (float*)d_out;
  (void)d_ws; (void)ws_size; (void)in_sizes; (void)n_in; (void)out_size;
  qlin_mfma_kernel<<<dim3(NWG), dim3(256), 0, stream>>>(x, pw, sc, out);
}

// Round 6
// 704.346 us; speedup vs baseline: 1.3470x; 1.2216x over previous
//
#include <hip/hip_runtime.h>
#include <hip/hip_bf16.h>

// Ternary-quantized linear: out[M,N] = x[M,K] . W^T,  W[n,k] = q[n,k]*scale[n].
// R6: ws-branch. Pre-pass converts x->bf16 and tight-packs weights into d_ws;
//     main GEMM stages A via global_load_lds (pre-swizzled global source, linear
//     LDS dest, XOR-swizzled read) and B via ONE global_load_lds per wave.
//     Wave tile 128x64 (unpack amortized 8 MFMAs/weight). Double-buffered LDS,
//     stage-before-compute, 1 barrier/kt. Fallback = R5 fused kernel.

#define M_DIM 8192
#define N_DIM 11008
#define K_DIM 4096
#define BM 128
#define BN 256
#define BK 64
#define KT 64
#define NB_N (N_DIM / BN)          // 43
#define NWG ((M_DIM / BM) * NB_N)  // 2752, %8 == 0

#define XBF_BYTES ((size_t)M_DIM * K_DIM * 2)        // 67108864
#define BT_BYTES  ((size_t)N_DIM * K_DIM / 4)        // 11272192
#define WS_NEED   (XBF_BYTES + BT_BYTES)

typedef __attribute__((ext_vector_type(8))) short bf16x8;
typedef __attribute__((ext_vector_type(4))) float f32x4;

__device__ inline unsigned int bf16b(float f) {
  union { __hip_bfloat16 h; unsigned short u; } cv;
  cv.h = __float2bfloat16(f);
  return (unsigned int)cv.u;
}

__device__ __forceinline__ void gload_lds16(const void* g, void* l) {
  __builtin_amdgcn_global_load_lds(
      (const __attribute__((address_space(1))) unsigned int*)g,
      (__attribute__((address_space(3))) unsigned int*)l, 16, 0, 0);
}

// ---------------- pre-pass: x fp32->bf16 ; PW one-byte-per-int32 -> tight bytes
#define XCVT_BLOCKS 16384   // 16384*256*8 = 33554432 floats
#define PACK_BLOCKS 5504    // 5504*256*8  = 11272192 int32s
__global__ __launch_bounds__(256)
void prep_kernel(const float* __restrict__ X, const int* __restrict__ PW,
                 unsigned short* __restrict__ Xbf, unsigned char* __restrict__ Bt) {
  const int b = blockIdx.x;
  if (b < XCVT_BLOCKS) {
    const size_t i8 = ((size_t)b * 256 + threadIdx.x) * 8;
    float4 a = *(const float4*)(X + i8);
    float4 c = *(const float4*)(X + i8 + 4);
    uint4 o;
    o.x = bf16b(a.x) | (bf16b(a.y) << 16);
    o.y = bf16b(a.z) | (bf16b(a.w) << 16);
    o.z = bf16b(c.x) | (bf16b(c.y) << 16);
    o.w = bf16b(c.z) | (bf16b(c.w) << 16);
    *(uint4*)(Xbf + i8) = o;
  } else {
    const size_t i8 = ((size_t)(b - XCVT_BLOCKS) * 256 + threadIdx.x) * 8;
    int4 p = *(const int4*)(PW + i8);
    int4 q = *(const int4*)(PW + i8 + 4);
    uint2 o;
    o.x = (unsigned)(p.x & 255) | ((unsigned)(p.y & 255) << 8) |
          ((unsigned)(p.z & 255) << 16) | ((unsigned)(p.w & 255) << 24);
    o.y = (unsigned)(q.x & 255) | ((unsigned)(q.y & 255) << 8) |
          ((unsigned)(q.z & 255) << 16) | ((unsigned)(q.w & 255) << 24);
    *(uint2*)(Bt + i8) = o;
  }
}

// ---------------- main MFMA GEMM (A bf16 from ws, B tight-packed from ws) ----
__global__ __launch_bounds__(256, 2)
void qlin_main_kernel(const unsigned short* __restrict__ Xbf,
                      const unsigned char* __restrict__ Bt,
                      const float* __restrict__ SC, float* __restrict__ OUT) {
  __shared__ unsigned short As[2][BM * BK];  // 2 x 16 KB, 128B rows, XOR-swizzled
  __shared__ unsigned char  Bs[2][BN * 16];  // 2 x 4 KB, packed, linear

  const int tid = threadIdx.x;
  const int lane = tid & 63;
  const int w = tid >> 6;

  const int wg = blockIdx.x;
  const int swz = (wg & 7) * (NWG / 8) + (wg >> 3);
  const int bm = swz / NB_N;
  const int bn = swz - bm * NB_N;

  // ---- A stage: 4 gload_lds/thread; linear LDS dest = wave base + lane*16.
  // LDS offset o = i*1024 + lane*16 -> row = w*32+i*8+(lane>>3), slot = lane&7.
  // Source chunk c = slot ^ (row&7); row&7 == lane>>3.
  const int l3 = lane >> 3;
  const int asrc_c = (lane & 7) ^ l3;
  const char* ab0 = (const char*)Xbf +
      (size_t)(bm * BM + w * 32 + l3) * (K_DIM * 2) + asrc_c * 16;
  // ---- B stage: 1 gload_lds/wave; row (= W output col) w*64+lane, 16B per kt.
  const char* bb = (const char*)Bt + (size_t)(bn * BN + w * 64 + lane) * (K_DIM / 4);

  unsigned short* adst0 = &As[0][w * 2048];  // 4 KB per wave (2048 ushorts)
  unsigned short* adst1 = &As[1][w * 2048];
  unsigned char* bdst0 = &Bs[0][w * 1024];
  unsigned char* bdst1 = &Bs[1][w * 1024];

#define STAGE(AD, BD, KT_) do {                                   \
    gload_lds16(ab0 + (KT_)*128,              (AD));              \
    gload_lds16(ab0 + (KT_)*128 + 1*65536,    (AD) + 512);        \
    gload_lds16(ab0 + (KT_)*128 + 2*65536,    (AD) + 1024);       \
    gload_lds16(ab0 + (KT_)*128 + 3*65536,    (AD) + 1536);       \
    gload_lds16(bb  + (KT_)*16,               (BD));              \
  } while (0)

  f32x4 acc[8][4];
#pragma unroll
  for (int i = 0; i < 8; ++i)
#pragma unroll
    for (int j = 0; j < 4; ++j) acc[i][j] = (f32x4){0.f, 0.f, 0.f, 0.f};

  // ---- fragment read geometry ----
  const int l4 = lane >> 4;                 // 0..3
  const int axor = lane & 7;                // row&7 for A-frag rows
  const int arow = (lane & 15) * 128;       // A row byte offset (within m-tile)
  const int hb = l4 >> 1;                   // B dword-pair select
  const unsigned hoff = (unsigned)(l4 & 1) * 16;  // B 16-bit half select
  const int rbase = (w * 64 + (lane & 15)) * 16 + hb * 4;

#define COMPUTE(B_) do {                                                        \
    _Pragma("unroll")                                                           \
    for (int kk = 0; kk < 2; ++kk) {                                            \
      bf16x8 af[8];                                                             \
      _Pragma("unroll")                                                         \
      for (int m = 0; m < 8; ++m)                                               \
        af[m] = *(const bf16x8*)((const char*)As[B_] + m * 2048 + arow +        \
                                 (((kk * 4 + l4) ^ axor) << 4));                \
      _Pragma("unroll")                                                         \
      for (int n = 0; n < 4; ++n) {                                             \
        const unsigned d = *(const unsigned*)(&Bs[B_][rbase + n * 256 + kk * 8]); \
        const unsigned w16 = (d >> hoff) & 0xFFFFu;                             \
        const unsigned u = w16 | (w16 << 14);                                   \
        union { uint4 s; bf16x8 v; } bfr;                                       \
        bfr.s.x = ((u << 14) & 0xC000C000u) + 0x40004000u;                      \
        bfr.s.y = ((u << 10) & 0xC000C000u) + 0x40004000u;                      \
        bfr.s.z = ((u << 6)  & 0xC000C000u) + 0x40004000u;                      \
        bfr.s.w = ((u << 2)  & 0xC000C000u) + 0x40004000u;                      \
        _Pragma("unroll")                                                       \
        for (int m = 0; m < 8; ++m)                                             \
          acc[m][n] = __builtin_amdgcn_mfma_f32_16x16x32_bf16(af[m], bfr.v,     \
                                                              acc[m][n], 0, 0, 0); \
      }                                                                         \
    }                                                                           \
  } while (0)

  STAGE(adst0, bdst0, 0);
  __syncthreads();
  for (int kt = 0; kt < KT; kt += 2) {
    STAGE(adst1, bdst1, kt + 1);
    COMPUTE(0);
    __syncthreads();
    if (kt + 2 < KT) STAGE(adst0, bdst0, kt + 2);
    COMPUTE(1);
    __syncthreads();
  }
#undef STAGE
#undef COMPUTE

  // ---- epilogue: acc * (-0.5*scale[col]); C/D: col=lane&15, row=(lane>>4)*4+r
  const int gc0 = bn * BN + w * 64 + (lane & 15);
  const int gr0 = bm * BM + (l4 << 2);
  float sc[4];
#pragma unroll
  for (int n = 0; n < 4; ++n) sc[n] = -0.5f * SC[gc0 + n * 16];
#pragma unroll
  for (int m = 0; m < 8; ++m)
#pragma unroll
    for (int n = 0; n < 4; ++n)
#pragma unroll
      for (int r = 0; r < 4; ++r)
        OUT[(size_t)(gr0 + m * 16 + r) * N_DIM + gc0 + n * 16] = acc[m][n][r] * sc[n];
}

// ---------------- fallback: R5 fused kernel (used if ws too small) ----------
#define BSTRIDE 20
__global__ __launch_bounds__(256, 2)
void qlin_fused_kernel(const float* __restrict__ X, const int* __restrict__ PW,
                       const float* __restrict__ SC, float* __restrict__ OUT) {
  __shared__ unsigned short Asf[BM * BK];
  __shared__ unsigned char Bp[BN * BSTRIDE];

  const int tid = threadIdx.x;
  const int wg = blockIdx.x;
  const int swz = (wg & 7) * (NWG / 8) + (wg >> 3);
  const int bm = swz / NB_N;
  const int bn = swz - bm * NB_N;

  const int lane = tid & 63;
  const int wave = tid >> 6;
  const int wr = wave >> 1;
  const int wc = wave & 1;

  const int arow = tid >> 3;
  const int ac8  = tid & 7;
  const float* xptr = X + (size_t)(bm * BM + arow) * K_DIM + ac8 * 8;
  const unsigned int aswz = ((unsigned)arow & 7u) << 4;

  const int bc  = tid & 3;
  const int br0 = tid >> 2;
  const int* pwptr = PW + (size_t)(bn * BN + br0) * (K_DIM / 4) + bc * 4;
  const int bwoff = (bc & 1) * 8 + (bc >> 1) * 2;

  f32x4 acc[4][8];
#pragma unroll
  for (int i = 0; i < 4; ++i)
#pragma unroll
    for (int j = 0; j < 8; ++j) acc[i][j] = (f32x4){0.f, 0.f, 0.f, 0.f};

  float4 av[4][2];
  int4 bv[4];
#pragma unroll
  for (int j = 0; j < 4; ++j) {
    av[j][0] = *(const float4*)(xptr + (size_t)(32 * j) * K_DIM);
    av[j][1] = *(const float4*)(xptr + (size_t)(32 * j) * K_DIM + 4);
  }
#pragma unroll
  for (int j = 0; j < 4; ++j)
    bv[j] = *(const int4*)(pwptr + (size_t)(64 * j) * (K_DIM / 4));

  for (int kt = 0; kt < KT; ++kt) {
    __syncthreads();
#pragma unroll
    for (int j = 0; j < 4; ++j) {
      uint4 wv;
      wv.x = bf16b(av[j][0].x) | (bf16b(av[j][0].y) << 16);
      wv.y = bf16b(av[j][0].z) | (bf16b(av[j][0].w) << 16);
      wv.z = bf16b(av[j][1].x) | (bf16b(av[j][1].y) << 16);
      wv.w = bf16b(av[j][1].z) | (bf16b(av[j][1].w) << 16);
      *(uint4*)((char*)Asf + (arow + 32 * j) * 128 + (((unsigned)ac8 * 16u) ^ aswz)) = wv;
    }
#pragma unroll
    for (int j = 0; j < 4; ++j) {
      const unsigned int ulo = ((unsigned)bv[j].x & 255u) | (((unsigned)bv[j].y & 255u) << 8);
      const unsigned int uhi = ((unsigned)bv[j].z & 255u) | (((unsigned)bv[j].w & 255u) << 8);
      unsigned char* dst = Bp + (br0 + 64 * j) * BSTRIDE + bwoff;
      *(unsigned short*)(dst)     = (unsigned short)ulo;
      *(unsigned short*)(dst + 4) = (unsigned short)uhi;
    }
    __syncthreads();

    if (kt + 1 < KT) {
#pragma unroll
      for (int j = 0; j < 4; ++j) {
        av[j][0] = *(const float4*)(xptr + (kt + 1) * BK + (size_t)(32 * j) * K_DIM);
        av[j][1] = *(const float4*)(xptr + (kt + 1) * BK + (size_t)(32 * j) * K_DIM + 4);
      }
#pragma unroll
      for (int j = 0; j < 4; ++j)
        bv[j] = *(const int4*)(pwptr + (kt + 1) * 16 + (size_t)(64 * j) * (K_DIM / 4));
    }

    const int bh = lane >> 4;
    const int bcol0 = wc * 128 + (lane & 15);
    unsigned int d[8];
#pragma unroll
    for (int n = 0; n < 8; ++n)
      d[n] = *(const unsigned int*)(Bp + (bcol0 + n * 16) * BSTRIDE + bh * 4);

    const unsigned int rswz = ((unsigned)lane & 7u) << 4;
#pragma unroll
    for (int kk = 0; kk < 2; ++kk) {
      bf16x8 af[4];
      const unsigned int coff = (((unsigned)(kk * 4 + (lane >> 4))) * 16u) ^ rswz;
#pragma unroll
      for (int m = 0; m < 4; ++m)
        af[m] = *(const bf16x8*)((const char*)Asf + (wr * 64 + m * 16 + (lane & 15)) * 128 + coff);
#pragma unroll
      for (int n = 0; n < 8; ++n) {
        const unsigned int w16 = kk ? (d[n] >> 16) : (d[n] & 0xFFFFu);
        const unsigned int u = w16 | (w16 << 14);
        union { uint4 s; bf16x8 v; } bfr;
        bfr.s.x = ((u << 14) & 0xC000C000u) + 0x40004000u;
        bfr.s.y = ((u << 10) & 0xC000C000u) + 0x40004000u;
        bfr.s.z = ((u << 6)  & 0xC000C000u) + 0x40004000u;
        bfr.s.w = ((u << 2)  & 0xC000C000u) + 0x40004000u;
#pragma unroll
        for (int m = 0; m < 4; ++m)
          acc[m][n] = __builtin_amdgcn_mfma_f32_16x16x32_bf16(af[m], bfr.v, acc[m][n], 0, 0, 0);
      }
    }
  }

  const int gc0 = bn * BN + wc * 128 + (lane & 15);
  const int gr0 = bm * BM + wr * 64 + ((lane >> 4) << 2);
  float sc[8];
#pragma unroll
  for (int n = 0; n < 8; ++n) sc[n] = -0.5f * SC[gc0 + n * 16];
#pragma unroll
  for (int m = 0; m < 4; ++m)
#pragma unroll
    for (int n = 0; n < 8; ++n)
#pragma unroll
      for (int r = 0; r < 4; ++r)
        OUT[(size_t)(gr0 + m * 16 + r) * N_DIM + gc0 + n * 16] = acc[m][n][r] * sc[n];
}

extern "C" void kernel_launch(void* const* d_in, const int* in_sizes, int n_in,
                              void* d_out, int out_size, void* d_ws, size_t ws_size,
                              hipStream_t stream) {
  const float* x  = (const float*)d_in[0];
  const int*   pw = (const int*)d_in[1];
  const float* sc = (const float*)d_in[2];
  float* out = (float*)d_out;
  (void)in_sizes; (void)n_in; (void)out_size;

  if (ws_size >= WS_NEED) {
    unsigned short* xbf = (unsigned short*)d_ws;
    unsigned char* bt = (unsigned char*)d_ws + XBF_BYTES;
    prep_kernel<<<dim3(XCVT_BLOCKS + PACK_BLOCKS), dim3(256), 0, stream>>>(x, pw, xbf, bt);
    qlin_main_kernel<<<dim3(NWG), dim3(256), 0, stream>>>(xbf, bt, sc, out);
  } else {
    qlin_fused_kernel<<<dim3(NWG), dim3(256), 0, stream>>>(x, pw, sc, out);
  }
}

// Round 7
// 637.569 us; speedup vs baseline: 1.4881x; 1.1047x over previous
//
#include <hip/hip_runtime.h>
#include <hip/hip_bf16.h>

// Ternary-quantized linear: out[M,N] = x[M,K] . W^T,  W[n,k] = q[n,k]*scale[n].
// R7: counted-vmcnt pipeline (T4). 3-buffer LDS ring, ONE raw s_barrier per kt,
//     s_waitcnt vmcnt(5) (never 0 in main loop) so next-tile global_load_lds
//     stay in flight across the barrier. Removes the __syncthreads vmcnt(0)
//     drain (the m97-structure ~20% stall). Pre-pass (x->bf16, W tight-pack)
//     and fragment geometry unchanged from R6. Fallback = R5 fused kernel.

#define M_DIM 8192
#define N_DIM 11008
#define K_DIM 4096
#define BM 128
#define BN 256
#define BK 64
#define KT 64
#define NB_N (N_DIM / BN)          // 43
#define NWG ((M_DIM / BM) * NB_N)  // 2752, %8 == 0

#define XBF_BYTES ((size_t)M_DIM * K_DIM * 2)        // 67108864
#define BT_BYTES  ((size_t)N_DIM * K_DIM / 4)        // 11272192
#define WS_NEED   (XBF_BYTES + BT_BYTES)

typedef __attribute__((ext_vector_type(8))) short bf16x8;
typedef __attribute__((ext_vector_type(4))) float f32x4;

__device__ inline unsigned int bf16b(float f) {
  union { __hip_bfloat16 h; unsigned short u; } cv;
  cv.h = __float2bfloat16(f);
  return (unsigned int)cv.u;
}

__device__ __forceinline__ void gload_lds16(const void* g, void* l) {
  __builtin_amdgcn_global_load_lds(
      (const __attribute__((address_space(1))) unsigned int*)g,
      (__attribute__((address_space(3))) unsigned int*)l, 16, 0, 0);
}

// ---------------- pre-pass: x fp32->bf16 ; PW one-byte-per-int32 -> tight bytes
#define XCVT_BLOCKS 16384   // 16384*256*8 = 33554432 floats
#define PACK_BLOCKS 5504    // 5504*256*8  = 11272192 int32s
__global__ __launch_bounds__(256)
void prep_kernel(const float* __restrict__ X, const int* __restrict__ PW,
                 unsigned short* __restrict__ Xbf, unsigned char* __restrict__ Bt) {
  const int b = blockIdx.x;
  if (b < XCVT_BLOCKS) {
    const size_t i8 = ((size_t)b * 256 + threadIdx.x) * 8;
    float4 a = *(const float4*)(X + i8);
    float4 c = *(const float4*)(X + i8 + 4);
    uint4 o;
    o.x = bf16b(a.x) | (bf16b(a.y) << 16);
    o.y = bf16b(a.z) | (bf16b(a.w) << 16);
    o.z = bf16b(c.x) | (bf16b(c.y) << 16);
    o.w = bf16b(c.z) | (bf16b(c.w) << 16);
    *(uint4*)(Xbf + i8) = o;
  } else {
    const size_t i8 = ((size_t)(b - XCVT_BLOCKS) * 256 + threadIdx.x) * 8;
    int4 p = *(const int4*)(PW + i8);
    int4 q = *(const int4*)(PW + i8 + 4);
    uint2 o;
    o.x = (unsigned)(p.x & 255) | ((unsigned)(p.y & 255) << 8) |
          ((unsigned)(p.z & 255) << 16) | ((unsigned)(p.w & 255) << 24);
    o.y = (unsigned)(q.x & 255) | ((unsigned)(q.y & 255) << 8) |
          ((unsigned)(q.z & 255) << 16) | ((unsigned)(q.w & 255) << 24);
    *(uint2*)(Bt + i8) = o;
  }
}

// ---------------- main MFMA GEMM (A bf16 from ws, B tight-packed from ws) ----
__global__ __launch_bounds__(256, 2)
void qlin_main_kernel(const unsigned short* __restrict__ Xbf,
                      const unsigned char* __restrict__ Bt,
                      const float* __restrict__ SC, float* __restrict__ OUT) {
  __shared__ unsigned short As[3][BM * BK];  // 3 x 16 KB ring, 128B rows
  __shared__ unsigned char  Bs[3][BN * 16];  // 3 x 4 KB ring, packed, linear

  const int tid = threadIdx.x;
  const int lane = tid & 63;
  const int w = tid >> 6;

  const int wg = blockIdx.x;
  const int swz = (wg & 7) * (NWG / 8) + (wg >> 3);
  const int bm = swz / NB_N;
  const int bn = swz - bm * NB_N;

  // ---- A stage: 4 gload_lds/thread; linear LDS dest = wave base + lane*16.
  // LDS offset o = i*1024 + lane*16 -> row = w*32+i*8+(lane>>3), slot = lane&7.
  // Source chunk c = slot ^ (row&7); row&7 == lane>>3 (m173 pre-swizzled src).
  const int l3 = lane >> 3;
  const int asrc_c = (lane & 7) ^ l3;
  const char* ab0 = (const char*)Xbf +
      (size_t)(bm * BM + w * 32 + l3) * (K_DIM * 2) + asrc_c * 16;
  // ---- B stage: 1 gload_lds/wave; row (= W output col) w*64+lane, 16B per kt.
  const char* bb = (const char*)Bt + (size_t)(bn * BN + w * 64 + lane) * (K_DIM / 4);

#define STAGE(IDX, KT_) do {                                           \
    unsigned short* ad_ = &As[IDX][w * 2048];                          \
    unsigned char* bd_ = &Bs[IDX][w * 1024];                           \
    gload_lds16(ab0 + (KT_)*128,           ad_);                       \
    gload_lds16(ab0 + (KT_)*128 + 65536,   ad_ + 512);                 \
    gload_lds16(ab0 + (KT_)*128 + 131072,  ad_ + 1024);                \
    gload_lds16(ab0 + (KT_)*128 + 196608,  ad_ + 1536);                \
    gload_lds16(bb  + (KT_)*16,            bd_);                       \
  } while (0)

  f32x4 acc[8][4];
#pragma unroll
  for (int i = 0; i < 8; ++i)
#pragma unroll
    for (int j = 0; j < 4; ++j) acc[i][j] = (f32x4){0.f, 0.f, 0.f, 0.f};

  // ---- fragment read geometry ----
  const int l4 = lane >> 4;                 // 0..3
  const int axor = lane & 7;                // row&7 for A-frag chunk XOR
  const int arow = (lane & 15) * 128;       // A row byte offset (within m-tile)
  const int hb = l4 >> 1;                   // B dword-pair select
  const unsigned hoff = (unsigned)(l4 & 1) * 16;  // B 16-bit half select
  const int rbase = (w * 64 + (lane & 15)) * 16 + hb * 4;

#define COMPUTE(B_) do {                                                        \
    const char* asb_ = (const char*)&As[B_][0];                                 \
    const unsigned char* bsb_ = &Bs[B_][0];                                     \
    _Pragma("unroll")                                                           \
    for (int kk = 0; kk < 2; ++kk) {                                            \
      bf16x8 af[8];                                                             \
      _Pragma("unroll")                                                         \
      for (int m = 0; m < 8; ++m)                                               \
        af[m] = *(const bf16x8*)(asb_ + m * 2048 + arow +                       \
                                 (((kk * 4 + l4) ^ axor) << 4));                \
      _Pragma("unroll")                                                         \
      for (int n = 0; n < 4; ++n) {                                             \
        const unsigned d = *(const unsigned*)(bsb_ + rbase + n * 256 + kk * 8); \
        const unsigned w16 = (d >> hoff) & 0xFFFFu;                             \
        const unsigned u = w16 | (w16 << 14);                                   \
        union { uint4 s; bf16x8 v; } bfr;                                       \
        bfr.s.x = ((u << 14) & 0xC000C000u) + 0x40004000u;                      \
        bfr.s.y = ((u << 10) & 0xC000C000u) + 0x40004000u;                      \
        bfr.s.z = ((u << 6)  & 0xC000C000u) + 0x40004000u;                      \
        bfr.s.w = ((u << 2)  & 0xC000C000u) + 0x40004000u;                      \
        _Pragma("unroll")                                                       \
        for (int m = 0; m < 8; ++m)                                             \
          acc[m][n] = __builtin_amdgcn_mfma_f32_16x16x32_bf16(af[m], bfr.v,     \
                                                              acc[m][n], 0, 0, 0); \
      }                                                                         \
    }                                                                           \
  } while (0)

  // ---- main loop: 3-buffer ring, counted vmcnt, 1 raw barrier per kt ----
  STAGE(0, 0);                                   // 5 loads in flight
  int cur = 0;
  for (int kt = 0; kt < KT - 1; ++kt) {
    const int nxt = (cur == 2) ? 0 : cur + 1;
    STAGE(nxt, kt + 1);                          // 10 in flight
    asm volatile("s_waitcnt vmcnt(5)" ::: "memory");   // cur's 5 done; nxt's stay
    asm volatile("s_waitcnt lgkmcnt(0)" ::: "memory"); // prev reads returned
    __builtin_amdgcn_s_barrier();                // all waves: cur ready
    COMPUTE(cur);
    cur = nxt;
  }
  asm volatile("s_waitcnt vmcnt(0)" ::: "memory");     // tail: last buffer
  asm volatile("s_waitcnt lgkmcnt(0)" ::: "memory");
  __builtin_amdgcn_s_barrier();
  COMPUTE(cur);
#undef STAGE
#undef COMPUTE

  // ---- epilogue: acc * (-0.5*scale[col]); C/D: col=lane&15, row=(lane>>4)*4+r
  const int gc0 = bn * BN + w * 64 + (lane & 15);
  const int gr0 = bm * BM + (l4 << 2);
  float sc[4];
#pragma unroll
  for (int n = 0; n < 4; ++n) sc[n] = -0.5f * SC[gc0 + n * 16];
#pragma unroll
  for (int m = 0; m < 8; ++m)
#pragma unroll
    for (int n = 0; n < 4; ++n)
#pragma unroll
      for (int r = 0; r < 4; ++r)
        OUT[(size_t)(gr0 + m * 16 + r) * N_DIM + gc0 + n * 16] = acc[m][n][r] * sc[n];
}

// ---------------- fallback: R5 fused kernel (used if ws too small) ----------
#define BSTRIDE 20
__global__ __launch_bounds__(256, 2)
void qlin_fused_kernel(const float* __restrict__ X, const int* __restrict__ PW,
                       const float* __restrict__ SC, float* __restrict__ OUT) {
  __shared__ unsigned short Asf[BM * BK];
  __shared__ unsigned char Bp[BN * BSTRIDE];

  const int tid = threadIdx.x;
  const int wg = blockIdx.x;
  const int swz = (wg & 7) * (NWG / 8) + (wg >> 3);
  const int bm = swz / NB_N;
  const int bn = swz - bm * NB_N;

  const int lane = tid & 63;
  const int wave = tid >> 6;
  const int wr = wave >> 1;
  const int wc = wave & 1;

  const int arow = tid >> 3;
  const int ac8  = tid & 7;
  const float* xptr = X + (size_t)(bm * BM + arow) * K_DIM + ac8 * 8;
  const unsigned int aswz = ((unsigned)arow & 7u) << 4;

  const int bc  = tid & 3;
  const int br0 = tid >> 2;
  const int* pwptr = PW + (size_t)(bn * BN + br0) * (K_DIM / 4) + bc * 4;
  const int bwoff = (bc & 1) * 8 + (bc >> 1) * 2;

  f32x4 acc[4][8];
#pragma unroll
  for (int i = 0; i < 4; ++i)
#pragma unroll
    for (int j = 0; j < 8; ++j) acc[i][j] = (f32x4){0.f, 0.f, 0.f, 0.f};

  float4 av[4][2];
  int4 bv[4];
#pragma unroll
  for (int j = 0; j < 4; ++j) {
    av[j][0] = *(const float4*)(xptr + (size_t)(32 * j) * K_DIM);
    av[j][1] = *(const float4*)(xptr + (size_t)(32 * j) * K_DIM + 4);
  }
#pragma unroll
  for (int j = 0; j < 4; ++j)
    bv[j] = *(const int4*)(pwptr + (size_t)(64 * j) * (K_DIM / 4));

  for (int kt = 0; kt < KT; ++kt) {
    __syncthreads();
#pragma unroll
    for (int j = 0; j < 4; ++j) {
      uint4 wv;
      wv.x = bf16b(av[j][0].x) | (bf16b(av[j][0].y) << 16);
      wv.y = bf16b(av[j][0].z) | (bf16b(av[j][0].w) << 16);
      wv.z = bf16b(av[j][1].x) | (bf16b(av[j][1].y) << 16);
      wv.w = bf16b(av[j][1].z) | (bf16b(av[j][1].w) << 16);
      *(uint4*)((char*)Asf + (arow + 32 * j) * 128 + (((unsigned)ac8 * 16u) ^ aswz)) = wv;
    }
#pragma unroll
    for (int j = 0; j < 4; ++j) {
      const unsigned int ulo = ((unsigned)bv[j].x & 255u) | (((unsigned)bv[j].y & 255u) << 8);
      const unsigned int uhi = ((unsigned)bv[j].z & 255u) | (((unsigned)bv[j].w & 255u) << 8);
      unsigned char* dst = Bp + (br0 + 64 * j) * BSTRIDE + bwoff;
      *(unsigned short*)(dst)     = (unsigned short)ulo;
      *(unsigned short*)(dst + 4) = (unsigned short)uhi;
    }
    __syncthreads();

    if (kt + 1 < KT) {
#pragma unroll
      for (int j = 0; j < 4; ++j) {
        av[j][0] = *(const float4*)(xptr + (kt + 1) * BK + (size_t)(32 * j) * K_DIM);
        av[j][1] = *(const float4*)(xptr + (kt + 1) * BK + (size_t)(32 * j) * K_DIM + 4);
      }
#pragma unroll
      for (int j = 0; j < 4; ++j)
        bv[j] = *(const int4*)(pwptr + (kt + 1) * 16 + (size_t)(64 * j) * (K_DIM / 4));
    }

    const int bh = lane >> 4;
    const int bcol0 = wc * 128 + (lane & 15);
    unsigned int d[8];
#pragma unroll
    for (int n = 0; n < 8; ++n)
      d[n] = *(const unsigned int*)(Bp + (bcol0 + n * 16) * BSTRIDE + bh * 4);

    const unsigned int rswz = ((unsigned)lane & 7u) << 4;
#pragma unroll
    for (int kk = 0; kk < 2; ++kk) {
      bf16x8 af[4];
      const unsigned int coff = (((unsigned)(kk * 4 + (lane >> 4))) * 16u) ^ rswz;
#pragma unroll
      for (int m = 0; m < 4; ++m)
        af[m] = *(const bf16x8*)((const char*)Asf + (wr * 64 + m * 16 + (lane & 15)) * 128 + coff);
#pragma unroll
      for (int n = 0; n < 8; ++n) {
        const unsigned int w16 = kk ? (d[n] >> 16) : (d[n] & 0xFFFFu);
        const unsigned int u = w16 | (w16 << 14);
        union { uint4 s; bf16x8 v; } bfr;
        bfr.s.x = ((u << 14) & 0xC000C000u) + 0x40004000u;
        bfr.s.y = ((u << 10) & 0xC000C000u) + 0x40004000u;
        bfr.s.z = ((u << 6)  & 0xC000C000u) + 0x40004000u;
        bfr.s.w = ((u << 2)  & 0xC000C000u) + 0x40004000u;
#pragma unroll
        for (int m = 0; m < 4; ++m)
          acc[m][n] = __builtin_amdgcn_mfma_f32_16x16x32_bf16(af[m], bfr.v, acc[m][n], 0, 0, 0);
      }
    }
  }

  const int gc0 = bn * BN + wc * 128 + (lane & 15);
  const int gr0 = bm * BM + wr * 64 + ((lane >> 4) << 2);
  float sc[8];
#pragma unroll
  for (int n = 0; n < 8; ++n) sc[n] = -0.5f * SC[gc0 + n * 16];
#pragma unroll
  for (int m = 0; m < 4; ++m)
#pragma unroll
    for (int n = 0; n < 8; ++n)
#pragma unroll
      for (int r = 0; r < 4; ++r)
        OUT[(size_t)(gr0 + m * 16 + r) * N_DIM + gc0 + n * 16] = acc[m][n][r] * sc[n];
}

extern "C" void kernel_launch(void* const* d_in, const int* in_sizes, int n_in,
                              void* d_out, int out_size, void* d_ws, size_t ws_size,
                              hipStream_t stream) {
  const float* x  = (const float*)d_in[0];
  const int*   pw = (const int*)d_in[1];
  const float* sc = (const float*)d_in[2];
  float* out = (float*)d_out;
  (void)in_sizes; (void)n_in; (void)out_size;

  if (ws_size >= WS_NEED) {
    unsigned short* xbf = (unsigned short*)d_ws;
    unsigned char* bt = (unsigned char*)d_ws + XBF_BYTES;
    prep_kernel<<<dim3(XCVT_BLOCKS + PACK_BLOCKS), dim3(256), 0, stream>>>(x, pw, xbf, bt);
    qlin_main_kernel<<<dim3(NWG), dim3(256), 0, stream>>>(xbf, bt, sc, out);
  } else {
    qlin_fused_kernel<<<dim3(NWG), dim3(256), 0, stream>>>(x, pw, sc, out);
  }
}